// Round 10
// baseline (235.300 us; speedup 1.0000x reference)
//
#include <hip/hip_runtime.h>
#include <math.h>

#define N_NODES 20000
#define N_EDGES 50000
#define N_SLOTS 256   // N_PAIRS * 2 flattened targets
#define N_PAIRS 128
#define CAP 64        // max incident edges per slot (deg ~ Poisson(5))
#define MSTRIDE 16384 // floats per matrix slot in ws
#define NMAT 19
#define NPROD 10
#define TFLAG (1 << 30)

// ---------- helpers ----------
__device__ __forceinline__ float4 relu4(float4 v) {
    return make_float4(fmaxf(v.x, 0.f), fmaxf(v.y, 0.f), fmaxf(v.z, 0.f), fmaxf(v.w, 0.f));
}
__device__ __forceinline__ float4 add4(float4 a, float4 b) {
    return make_float4(a.x + b.x, a.y + b.y, a.z + b.z, a.w + b.w);
}
__device__ __forceinline__ void fma4(float4& acc, const float4 w, const float s) {
    acc.x = fmaf(w.x, s, acc.x); acc.y = fmaf(w.y, s, acc.y);
    acc.z = fmaf(w.z, s, acc.z); acc.w = fmaf(w.w, s, acc.w);
}
#define F4Z make_float4(0.f, 0.f, 0.f, 0.f)

// ===== 16-group K-split (512-thread k_layer): group g covers k-chunks [2g,2g+2) =====
// R9 lesson: 256-thr blocks = 1 wave/SIMD = zero latency hiding (44.7 us at 6% VALU).
// 512 thr gives 2 waves/SIMD and halves per-lane weight chains.
__device__ __forceinline__ float4 mv_ks1_g16(const float* __restrict__ WT,
                                             const float* __restrict__ xv128,
                                             int g, int jj) {
    const float4* W4 = (const float4*)WT;
    const float4* x4 = (const float4*)xv128;
    float4 acc = F4Z;
#pragma unroll
    for (int kk4 = 0; kk4 < 2; ++kk4) {
        int k4 = g * 2 + kk4;
        float4 xv = x4[k4];
        fma4(acc, W4[(k4 * 4 + 0) * 32 + jj], xv.x);
        fma4(acc, W4[(k4 * 4 + 1) * 32 + jj], xv.y);
        fma4(acc, W4[(k4 * 4 + 2) * 32 + jj], xv.z);
        fma4(acc, W4[(k4 * 4 + 3) * 32 + jj], xv.w);
    }
    return acc;
}
__device__ __forceinline__ float4 mv_ks1_g16_64(const float* __restrict__ WT,
                                                const float* __restrict__ xv128,
                                                int g, int jj) {
    const float4* W4 = (const float4*)WT;
    const float4* x4 = (const float4*)xv128;
    int j16 = jj & 15;
    float4 acc = F4Z;
#pragma unroll
    for (int kk4 = 0; kk4 < 2; ++kk4) {
        int k4 = g * 2 + kk4;
        float4 xv = x4[k4];
        fma4(acc, W4[(k4 * 4 + 0) * 16 + j16], xv.x);
        fma4(acc, W4[(k4 * 4 + 1) * 16 + j16], xv.y);
        fma4(acc, W4[(k4 * 4 + 2) * 16 + j16], xv.z);
        fma4(acc, W4[(k4 * 4 + 3) * 16 + j16], xv.w);
    }
    return acc;
}
// one accumulator set per barrier scope (spill guard — R8's 256-VGPR lesson)
__device__ __forceinline__ void mv8_g16(const float* __restrict__ WT,
                                        const float* __restrict__ xs,
                                        int g, int jj, float4* acc) {
    const float4* W4 = (const float4*)WT;
    const float4* x4 = (const float4*)xs;
#pragma unroll
    for (int kk4 = 0; kk4 < 2; ++kk4) {
        int k4 = g * 2 + kk4;
        float4 w0 = W4[(k4 * 4 + 0) * 32 + jj];
        float4 w1 = W4[(k4 * 4 + 1) * 32 + jj];
        float4 w2 = W4[(k4 * 4 + 2) * 32 + jj];
        float4 w3 = W4[(k4 * 4 + 3) * 32 + jj];
#pragma unroll
        for (int e = 0; e < 8; ++e) {
            float4 xv = x4[e * 32 + k4];
            fma4(acc[e], w0, xv.x); fma4(acc[e], w1, xv.y);
            fma4(acc[e], w2, xv.z); fma4(acc[e], w3, xv.w);
        }
    }
}
__device__ __forceinline__ float4 comb1_g16(const float4* pb, int jj) {
    float4 s = pb[jj];
#pragma unroll
    for (int gp = 1; gp < 16; ++gp) s = add4(s, pb[gp * 32 + jj]);
    return s;
}
__device__ __forceinline__ float4 comb8_g16(const float4* pb, int it, int jj) {
    float4 s = pb[it * 32 + jj];
#pragma unroll
    for (int gp = 1; gp < 16; ++gp) s = add4(s, pb[(gp * 8 + it) * 32 + jj]);
    return s;
}

// ---------- kernels ----------

// fused one-time prep: weight transposes (blocks 0..71), matrix products +
// fused biases (blocks 72..151), pairflag zero (block 0), per-slot edge scan (all)
__global__ __launch_bounds__(256) void k_prep_tr(
    const int* __restrict__ ei, const int* __restrict__ tp,
    const float* __restrict__ inW, const float* __restrict__ ftW,
    const float* __restrict__ teW2, const float* __restrict__ aiW,
    const float* __restrict__ aib,
    const float* __restrict__ aoW, const float* __restrict__ opW,
    const float* __restrict__ o1W, const float* __restrict__ o2W,
    const float* __restrict__ l1W, const float* __restrict__ l2W,
    const float* __restrict__ ftb, const float* __restrict__ teb2,
    float* __restrict__ WT, float* __restrict__ WP, float* __restrict__ WB,
    int* __restrict__ pairflag,
    int* __restrict__ cnt, int2* __restrict__ lst) {
    __shared__ float tile[32][129];
    __shared__ __align__(16) float As[128 * 128];   // 64 KB
    __shared__ __align__(16) float Bs[128 * 16];    // 8 KB
    __shared__ float bv_s[128];
    __shared__ int tps[N_SLOTS];
    __shared__ int lc;
    const int b = blockIdx.x;
    const int tid = threadIdx.x;
    if (tid == 0) lc = 0;
    if (b == 0 && tid < N_PAIRS) pairflag[tid] = 0;
    if (b < 72) {  // ---- transposes (block-uniform branch) ----
        int m, r0, rows;
        if (b < 68) { m = b >> 2; r0 = (b & 3) * 32; rows = 128; }
        else { int mm = b - 68; m = 17 + (mm >> 1); r0 = (mm & 1) * 32; rows = 64; }
        const float* src;
        if (m == 0) src = inW;
        else if (m <= 2) src = ftW + (m - 1) * MSTRIDE;
        else if (m <= 4) src = teW2 + (m - 3) * MSTRIDE;
        else if (m <= 10) src = aiW + (m - 5) * MSTRIDE;  // q0,k0,v0,q1,k1,v1
        else if (m <= 12) src = aoW + (m - 11) * MSTRIDE;
        else if (m <= 14) src = opW + (m - 13) * MSTRIDE;
        else if (m == 15) src = o1W;
        else if (m == 16) src = l1W;
        else if (m == 17) src = o2W;
        else src = l2W;
        float* dst = WT + m * MSTRIDE;
        for (int idx = tid; idx < 32 * 128; idx += 256) {
            int r = idx >> 7, c = idx & 127;
            tile[r][c] = src[(r0 + r) * 128 + c];
        }
        __syncthreads();
        for (int idx = tid; idx < 128 * 32; idx += 256) {
            int k = idx >> 5, jr = idx & 31;
            dst[k * rows + r0 + jr] = tile[jr][k];
        }
    } else if (b < 152) {  // ---- products PT = (A@B)^T, 8 blocks per product ----
        const int pidx = (b - 72) >> 3, mseg = (b - 72) & 7, m0 = mseg * 16;
        const int l = pidx / 5, t = pidx % 5;
        const float* A = aiW + l * 3 * MSTRIDE +
                         ((t == 0) ? 0 : (t <= 2) ? MSTRIDE : 2 * MSTRIDE);
        const float* B = ((t == 2 || t == 4) ? teW2 : ftW) + l * MSTRIDE;
        {
            const float4* A4 = (const float4*)A;
            float4* As4 = (float4*)As;
            for (int idx = tid; idx < 4096; idx += 256) As4[idx] = A4[idx];
            for (int idx = tid; idx < 2048; idx += 256) {
                int j = idx >> 4, mm = idx & 15;
                Bs[idx] = B[j * 128 + m0 + mm];
            }
            if (tid < 128) {
                float bb = ftb[l * 128 + tid];
                if (t != 0) bb += teb2[l * 128 + tid];
                bv_s[tid] = bb;
            }
        }
        __syncthreads();
        {
            const int i = tid & 127, half = tid >> 7;
            const float4* As4 = (const float4*)As;
            const float4* Bs4 = (const float4*)Bs;
            float4 accA = F4Z, accB = F4Z;  // 8 outputs: m = m0+half*8 + 0..7
#pragma unroll 4
            for (int j4 = 0; j4 < 32; ++j4) {
                float4 a4 = As4[i * 32 + j4];
#pragma unroll
                for (int jo = 0; jo < 4; ++jo) {
                    int j = j4 * 4 + jo;
                    float aj = (jo == 0) ? a4.x : (jo == 1) ? a4.y : (jo == 2) ? a4.z : a4.w;
                    float4 b0 = Bs4[j * 4 + half * 2 + 0];
                    float4 b1 = Bs4[j * 4 + half * 2 + 1];
                    fma4(accA, b0, aj);
                    fma4(accB, b1, aj);
                }
            }
            float* dst = WP + pidx * MSTRIDE;
            float o[8] = {accA.x, accA.y, accA.z, accA.w, accB.x, accB.y, accB.z, accB.w};
#pragma unroll
            for (int r = 0; r < 8; ++r) dst[(m0 + half * 8 + r) * 128 + i] = o[r];
        }
        if (mseg == 0 && (t == 0 || t == 1 || t == 3) && tid < 128) {
            const float4* As4 = (const float4*)As;
            const float4* bs4 = (const float4*)bv_s;
            float acc = 0.f;
#pragma unroll 4
            for (int j4 = 0; j4 < 32; ++j4) {
                float4 a4 = As4[tid * 32 + j4];
                float4 b4 = bs4[j4];
                acc = fmaf(a4.x, b4.x, fmaf(a4.y, b4.y, fmaf(a4.z, b4.z, fmaf(a4.w, b4.w, acc))));
            }
            int which = (t == 0) ? 0 : (t == 1) ? 1 : 2;
            WB[l * 384 + which * 128 + tid] = acc + aib[l * 384 + which * 128 + tid];
        }
    }
    for (int i = tid; i < N_SLOTS; i += 256) tps[i] = tp[i];
    __syncthreads();
    // ---- per-slot incident-edge scan ----
    const int u = tps[b];
    const int4* src4 = (const int4*)ei;
    const int4* dst4 = (const int4*)(ei + N_EDGES);
    for (int e4 = tid; e4 < N_EDGES / 4; e4 += 256) {
        int4 s = src4[e4];
        int4 d = dst4[e4];
        int ss[4] = {s.x, s.y, s.z, s.w};
        int dd[4] = {d.x, d.y, d.z, d.w};
#pragma unroll
        for (int t2 = 0; t2 < 4; ++t2) {
            if (ss[t2] == u || dd[t2] == u) {
                int nbr = (ss[t2] == u) ? dd[t2] : ss[t2];
                int pos = atomicAdd(&lc, 1);
                if (pos < CAP) lst[b * CAP + pos] = make_int2(e4 * 4 + t2, nbr);
            }
        }
    }
    __syncthreads();
    if (tid == 0) cnt[b] = lc;
    int c = min(lc, CAP);
    if (tid < c) {
        int2 en = lst[b * CAP + tid];
        bool ist = false;
        for (int t2 = 0; t2 < N_SLOTS; ++t2) ist |= (tps[t2] == en.y);
        if (ist) { en.y |= TFLAG; lst[b * CAP + tid] = en; }
    }
}

// one block (512 thr, 16 K-groups, 2 waves/SIMD) per slot. Folded products:
// q = WPq@x0 + bq', k = WkF@x0 + WkT@t1 + bk', v likewise. scores/v in LDS,
// fused reduce; layer 0 scatters relu(agg); layer 1 runs emb + pair heads.
__global__ __launch_bounds__(512) void k_layer(
    const float* __restrict__ nf, const float* __restrict__ x,
    const float* __restrict__ ts, const int* __restrict__ tp,
    const int* __restrict__ cnt, const int2* __restrict__ lst,
    const float* __restrict__ WT_in, const float* __restrict__ inb,
    const float* __restrict__ WT_ft, const float* __restrict__ ftb,
    const float* __restrict__ teW1, const float* __restrict__ teb1,
    const float* __restrict__ WPq, const float* __restrict__ WkF,
    const float* __restrict__ WkT, const float* __restrict__ WvF,
    const float* __restrict__ WvT, const float* __restrict__ WBl,
    const float* __restrict__ WT_ao, const float* __restrict__ aob,
    const float* __restrict__ WT_op, const float* __restrict__ opb,
    const float* __restrict__ WT_o1, const float* __restrict__ o1b,
    const float* __restrict__ WT_o2, const float* __restrict__ o2b,
    const float* __restrict__ WT_l1, const float* __restrict__ l1b,
    const float* __restrict__ WT_l2, const float* __restrict__ l2b,
    const float* __restrict__ l3W, const float* __restrict__ l3b,
    float* __restrict__ x_out, float* __restrict__ emb,
    int* __restrict__ pairflag, float* __restrict__ out, int layer) {
    __shared__ __align__(16) float xu[128], x0u[128], tfv[128], qv[128], sv[128];
    __shared__ __align__(16) float xs[8 * 128], t1s[8 * 128], x0s[8 * 128];
    __shared__ __align__(16) float4 pb[16 * 8 * 32];  // 64 KB partials
    __shared__ __align__(16) float vbl[CAP * 128];    // 32 KB
    __shared__ float scl[CAP * 4];
    __shared__ int nbr_s[8], tf_s[8];
    __shared__ float ts_s[8];
    __shared__ int win_s;
    const int slot = blockIdx.x, tid = threadIdx.x, g = tid >> 5, jj = tid & 31;
    const float scale = 0.17677669529663687f;  // 1/sqrt(32)
    const int u = tp[slot];
    const int c = min(cnt[slot], CAP);
    const float* bqp = WBl;          // fused q bias
    const float* bkp = WBl + 128;    // fused k bias
    const float* bvp = WBl + 256;    // fused v bias

    // ---- phase A: x0_u (layer 0), tf_u, q ----
    if (tid < 128) xu[tid] = (layer == 0) ? nf[(size_t)u * 128 + tid]
                                          : x[(size_t)u * 128 + tid];
    __syncthreads();
    const float* xeff = xu;
    if (layer == 0) {
        pb[g * 32 + jj] = mv_ks1_g16(WT_in, xu, g, jj);
        __syncthreads();
        if (g == 0)
            *(float4*)(x0u + jj * 4) = add4(comb1_g16(pb, jj), *(const float4*)(inb + jj * 4));
        xeff = x0u;
        __syncthreads();
    }
    pb[g * 32 + jj] = mv_ks1_g16(WT_ft, xeff, g, jj);
    __syncthreads();
    if (g == 0)
        *(float4*)(tfv + jj * 4) = add4(comb1_g16(pb, jj), *(const float4*)(ftb + jj * 4));
    __syncthreads();
    pb[g * 32 + jj] = mv_ks1_g16(WPq, xeff, g, jj);
    __syncthreads();
    if (g == 0)
        *(float4*)(qv + jj * 4) = add4(comb1_g16(pb, jj), *(const float4*)(bqp + jj * 4));
    __syncthreads();

    // ---- phase B: edge batches of 8 (items owned by groups g<8) ----
    for (int base = 0; base < c; base += 8) {
        if (tid < 8) {
            int i = base + tid;
            int2 en = (i < c) ? lst[slot * CAP + i] : make_int2(0, 0);
            nbr_s[tid] = en.y & ~TFLAG;
            tf_s[tid] = (en.y & TFLAG) ? 1 : 0;
            ts_s[tid] = (i < c) ? ts[en.x] : 0.f;
        }
        __syncthreads();
        if (tid < 256) {  // stage neighbor row + time-encoding layer-1 activation
            int e = tid >> 5, c0 = jj * 4;
            const float* srcp = (layer == 0) ? (nf + (size_t)nbr_s[e] * 128 + c0)
                                             : (x + (size_t)nbr_s[e] * 128 + c0);
            float4 v = *(const float4*)srcp;
            float* dstp = (layer == 0) ? xs : x0s;
            *(float4*)(dstp + e * 128 + c0) = v;
            float tse = ts_s[e];
            float4 w = *(const float4*)(teW1 + c0);
            float4 b = *(const float4*)(teb1 + c0);
            *(float4*)(t1s + e * 128 + c0) =
                make_float4(fmaxf(fmaf(tse, w.x, b.x), 0.f),
                            fmaxf(fmaf(tse, w.y, b.y), 0.f),
                            fmaxf(fmaf(tse, w.z, b.z), 0.f),
                            fmaxf(fmaf(tse, w.w, b.w), 0.f));
        }
        __syncthreads();
        if (layer == 0) {  // x0_nbr = inW @ nf[nbr] + inb; persist relu(x0)
            float4 acc[8] = {F4Z, F4Z, F4Z, F4Z, F4Z, F4Z, F4Z, F4Z};
            mv8_g16(WT_in, xs, g, jj, acc);
#pragma unroll
            for (int e = 0; e < 8; ++e) pb[(g * 8 + e) * 32 + jj] = acc[e];
            __syncthreads();
            if (g < 8) {
                float4 x0v = add4(comb8_g16(pb, g, jj), *(const float4*)(inb + jj * 4));
                *(float4*)(x0s + g * 128 + jj * 4) = x0v;
                if (base + g < c && !tf_s[g])
                    *(float4*)(x_out + (size_t)nbr_s[g] * 128 + jj * 4) = relu4(x0v);
            }
            __syncthreads();
        }
        float4 kk;
        {   // k-stage: ONE acc set live
            float4 acc[8] = {F4Z, F4Z, F4Z, F4Z, F4Z, F4Z, F4Z, F4Z};
            mv8_g16(WkF, x0s, g, jj, acc);
            mv8_g16(WkT, t1s, g, jj, acc);
#pragma unroll
            for (int e = 0; e < 8; ++e) pb[(g * 8 + e) * 32 + jj] = acc[e];
            __syncthreads();
            if (g < 8) kk = add4(comb8_g16(pb, g, jj), *(const float4*)(bkp + jj * 4));
            __syncthreads();
        }
        {   // v-stage: ONE acc set live
            float4 acc[8] = {F4Z, F4Z, F4Z, F4Z, F4Z, F4Z, F4Z, F4Z};
            mv8_g16(WvF, x0s, g, jj, acc);
            mv8_g16(WvT, t1s, g, jj, acc);
#pragma unroll
            for (int e = 0; e < 8; ++e) pb[(g * 8 + e) * 32 + jj] = acc[e];
            __syncthreads();
            if (g < 8 && base + g < c) {
                float4 vv = add4(comb8_g16(pb, g, jj), *(const float4*)(bvp + jj * 4));
                float4 q4 = *(const float4*)(qv + jj * 4);
                float pr = q4.x * kk.x + q4.y * kk.y + q4.z * kk.z + q4.w * kk.w;
                pr += __shfl_xor(pr, 1);
                pr += __shfl_xor(pr, 2);
                pr += __shfl_xor(pr, 4);  // sum over the 8 lanes of head jj>>3
                if ((jj & 7) == 0) scl[(base + g) * 4 + (jj >> 3)] = pr * scale;
                *(float4*)(vbl + (base + g) * 128 + jj * 4) = vv;
            }
            __syncthreads();  // before next batch restages LDS
        }
    }

    // ---- fused reduce ----
    if (tid < 128) {
        int h = tid >> 5;
        if (c > 0) {
            float m = -INFINITY;
            for (int i = 0; i < c; ++i) m = fmaxf(m, scl[i * 4 + h]);
            float l = 0.f, o = 0.f;
            for (int i = 0; i < c; ++i) {
                float p = __expf(scl[i * 4 + h] - m);
                l += p;
                o = fmaf(p, vbl[i * 128 + tid], o);
            }
            sv[tid] = o / l;
        } else {
            sv[tid] = 0.f;
        }
    }
    __syncthreads();
    pb[g * 32 + jj] = mv_ks1_g16(WT_ao, sv, g, jj);
    __syncthreads();
    if (g == 0) {
        float4 z4;
        if (c > 0) z4 = add4(comb1_g16(pb, jj), *(const float4*)(aob + jj * 4));
        else z4 = *(const float4*)(tfv + jj * 4);
        *(float4*)(xu + jj * 4) = z4;  // reuse xu as z
    }
    __syncthreads();
    pb[g * 32 + jj] = mv_ks1_g16(WT_op, xu, g, jj);
    __syncthreads();
    if (layer == 0) {
        if (g == 0) {
            float4 a = relu4(add4(comb1_g16(pb, jj), *(const float4*)(opb + jj * 4)));
            *(float4*)(x_out + (size_t)u * 128 + jj * 4) = a;
        }
        return;
    }
    // ---- layer 1: emb head ----
    if (g == 0)
        *(float4*)(x0u + jj * 4) =
            relu4(add4(comb1_g16(pb, jj), *(const float4*)(opb + jj * 4)));
    __syncthreads();
    pb[g * 32 + jj] = mv_ks1_g16(WT_o1, x0u, g, jj);
    __syncthreads();
    if (g == 0)
        *(float4*)(tfv + jj * 4) =
            relu4(add4(comb1_g16(pb, jj), *(const float4*)(o1b + jj * 4)));
    __syncthreads();
    pb[g * 32 + jj] = mv_ks1_g16_64(WT_o2, tfv, g, jj);
    __syncthreads();
    if (g == 0 && jj < 16) {
        *(float4*)(emb + (size_t)slot * 64 + jj * 4) =
            add4(comb1_g16(pb, jj), *(const float4*)(o2b + jj * 4));
        __threadfence();  // writers flush emb before the atomic
    }
    __syncthreads();
    // ---- pair handshake: last-arriving slot of pair computes the head ----
    if (tid == 0) win_s = atomicAdd(&pairflag[slot >> 1], 1);
    __syncthreads();
    if (win_s == 0) return;
    __threadfence();  // acquire: partner emb now device-visible
    const int p = slot >> 1;
    if (tid < 128)
        sv[tid] = (tid < 64) ? emb[(size_t)(2 * p) * 64 + tid]
                             : emb[(size_t)(2 * p + 1) * 64 + (tid - 64)];
    __syncthreads();
    pb[g * 32 + jj] = mv_ks1_g16(WT_l1, sv, g, jj);
    __syncthreads();
    if (g == 0)
        *(float4*)(xu + jj * 4) = relu4(add4(comb1_g16(pb, jj), *(const float4*)(l1b + jj * 4)));
    __syncthreads();
    pb[g * 32 + jj] = mv_ks1_g16_64(WT_l2, xu, g, jj);
    __syncthreads();
    if (g == 0 && jj < 16)
        *(float4*)(x0u + jj * 4) = relu4(add4(comb1_g16(pb, jj), *(const float4*)(l2b + jj * 4)));
    __syncthreads();
    if (tid < 64) {
        float v = x0u[tid] * l3W[tid];
        v += __shfl_xor(v, 1);
        v += __shfl_xor(v, 2);
        v += __shfl_xor(v, 4);
        v += __shfl_xor(v, 8);
        v += __shfl_xor(v, 16);
        v += __shfl_xor(v, 32);
        if (tid == 0) out[p] = 1.f / (1.f + __expf(-(v + l3b[0])));
    }
}

// ---------- launch ----------
extern "C" void kernel_launch(void* const* d_in, const int* in_sizes, int n_in,
                              void* d_out, int out_size, void* d_ws, size_t ws_size,
                              hipStream_t stream) {
    const float* nf  = (const float*)d_in[0];
    const int*   ei  = (const int*)d_in[1];
    const float* ts  = (const float*)d_in[2];
    const int*   tp  = (const int*)d_in[3];
    const float* inW = (const float*)d_in[4];
    const float* inb = (const float*)d_in[5];
    const float* teW1 = (const float*)d_in[6];
    const float* teb1 = (const float*)d_in[7];
    const float* teW2 = (const float*)d_in[8];
    const float* teb2 = (const float*)d_in[9];
    const float* aiW = (const float*)d_in[10];
    const float* aib = (const float*)d_in[11];
    const float* aoW = (const float*)d_in[12];
    const float* aob = (const float*)d_in[13];
    const float* ftW = (const float*)d_in[14];
    const float* ftb = (const float*)d_in[15];
    const float* opW = (const float*)d_in[16];
    const float* opb = (const float*)d_in[17];
    const float* o1W = (const float*)d_in[18];
    const float* o1b = (const float*)d_in[19];
    const float* o2W = (const float*)d_in[20];
    const float* o2b = (const float*)d_in[21];
    const float* l1W = (const float*)d_in[22];
    const float* l1b = (const float*)d_in[23];
    const float* l2W = (const float*)d_in[24];
    const float* l2b = (const float*)d_in[25];
    const float* l3W = (const float*)d_in[26];
    const float* l3b = (const float*)d_in[27];
    float* out = (float*)d_out;

    char* ws = (char*)d_ws;
    size_t off = 0;
    float* x    = (float*)(ws + off); off += (size_t)N_NODES * 128 * 4;   // 10.24 MB
    int*   cnt  = (int*)  (ws + off); off += N_SLOTS * 4;
    int2*  lst  = (int2*) (ws + off); off += (size_t)N_SLOTS * CAP * 8;
    float* emb  = (float*)(ws + off); off += N_SLOTS * 64 * 4;
    int*   pfl  = (int*)  (ws + off); off += N_PAIRS * 4;
    float* WT   = (float*)(ws + off); off += (size_t)NMAT * MSTRIDE * 4;  // 1.2 MB
    float* WP   = (float*)(ws + off); off += (size_t)NPROD * MSTRIDE * 4; // 640 KB
    float* WB   = (float*)(ws + off); off += 2 * 384 * 4;

    k_prep_tr<<<N_SLOTS, 256, 0, stream>>>(ei, tp, inW, ftW, teW2, aiW, aib,
                                           aoW, opW, o1W, o2W, l1W, l2W,
                                           ftb, teb2, WT, WP, WB, pfl, cnt, lst);

    for (int l = 0; l < 2; ++l) {
        const float* WT_ft = WT + (1 + l) * MSTRIDE;
        const float* WPq = WP + (l * 5 + 0) * MSTRIDE;
        const float* WkF = WP + (l * 5 + 1) * MSTRIDE;
        const float* WkT = WP + (l * 5 + 2) * MSTRIDE;
        const float* WvF = WP + (l * 5 + 3) * MSTRIDE;
        const float* WvT = WP + (l * 5 + 4) * MSTRIDE;
        const float* WT_ao = WT + (11 + l) * MSTRIDE;
        const float* WT_op = WT + (13 + l) * MSTRIDE;
        k_layer<<<N_SLOTS, 512, 0, stream>>>(
            nf, x, ts, tp, cnt, lst,
            WT, inb, WT_ft, ftb + l * 128, teW1 + l * 128, teb1 + l * 128,
            WPq, WkF, WkT, WvF, WvT, WB + l * 384,
            WT_ao, aob + l * 128, WT_op, opb + l * 128,
            WT + 15 * MSTRIDE, o1b, WT + 17 * MSTRIDE, o2b,
            WT + 16 * MSTRIDE, l1b, WT + 18 * MSTRIDE, l2b, l3W, l3b,
            x, emb, pfl, out, l);
    }
}

// Round 11
// 210.814 us; speedup vs baseline: 1.1162x; 1.1162x over previous
//
#include <hip/hip_runtime.h>
#include <math.h>

#define N_NODES 20000
#define N_EDGES 50000
#define N_SLOTS 256   // N_PAIRS * 2 flattened targets
#define N_PAIRS 128
#define CAP 64        // max incident edges per slot (deg ~ Poisson(5))
#define MSTRIDE 16384 // floats per transposed-matrix slot in ws
#define NMAT 19
#define TFLAG (1 << 30)

// ---------- helpers ----------
__device__ __forceinline__ float4 relu4(float4 v) {
    return make_float4(fmaxf(v.x, 0.f), fmaxf(v.y, 0.f), fmaxf(v.z, 0.f), fmaxf(v.w, 0.f));
}
__device__ __forceinline__ float4 add4(float4 a, float4 b) {
    return make_float4(a.x + b.x, a.y + b.y, a.z + b.z, a.w + b.w);
}
__device__ __forceinline__ void fma4(float4& acc, const float4 w, const float s) {
    acc.x = fmaf(w.x, s, acc.x); acc.y = fmaf(w.y, s, acc.y);
    acc.z = fmaf(w.z, s, acc.z); acc.w = fmaf(w.w, s, acc.w);
}
#define F4Z make_float4(0.f, 0.f, 0.f, 0.f)

// ===== 8-group K-split (256-thread blocks): group g covers k-chunks [4g,4g+4) =====
// Measured best config (R7 = 200.9 us). 512-thr (R10) and folded-product
// restructurings (R8/R9) all regressed — keep this shape.
__device__ __forceinline__ float4 mv_ks1_g8(const float* __restrict__ WT,
                                            const float* __restrict__ xv128,
                                            int g, int jj) {
    const float4* W4 = (const float4*)WT;
    const float4* x4 = (const float4*)xv128;
    float4 acc = F4Z;
#pragma unroll
    for (int kk4 = 0; kk4 < 4; ++kk4) {
        int k4 = g * 4 + kk4;
        float4 xv = x4[k4];
        fma4(acc, W4[(k4 * 4 + 0) * 32 + jj], xv.x);
        fma4(acc, W4[(k4 * 4 + 1) * 32 + jj], xv.y);
        fma4(acc, W4[(k4 * 4 + 2) * 32 + jj], xv.z);
        fma4(acc, W4[(k4 * 4 + 3) * 32 + jj], xv.w);
    }
    return acc;
}
__device__ __forceinline__ float4 mv_ks1_g8_64(const float* __restrict__ WT,
                                               const float* __restrict__ xv128,
                                               int g, int jj) {
    const float4* W4 = (const float4*)WT;
    const float4* x4 = (const float4*)xv128;
    int j16 = jj & 15;
    float4 acc = F4Z;
#pragma unroll
    for (int kk4 = 0; kk4 < 4; ++kk4) {
        int k4 = g * 4 + kk4;
        float4 xv = x4[k4];
        fma4(acc, W4[(k4 * 4 + 0) * 16 + j16], xv.x);
        fma4(acc, W4[(k4 * 4 + 1) * 16 + j16], xv.y);
        fma4(acc, W4[(k4 * 4 + 2) * 16 + j16], xv.z);
        fma4(acc, W4[(k4 * 4 + 3) * 16 + j16], xv.w);
    }
    return acc;
}
// one accumulator set per barrier scope (spill guard — R8's 256-VGPR lesson)
__device__ __forceinline__ void mv8_g8(const float* __restrict__ WT,
                                       const float* __restrict__ xs,
                                       int g, int jj, float4* acc) {
    const float4* W4 = (const float4*)WT;
    const float4* x4 = (const float4*)xs;
#pragma unroll
    for (int kk4 = 0; kk4 < 4; ++kk4) {
        int k4 = g * 4 + kk4;
        float4 w0 = W4[(k4 * 4 + 0) * 32 + jj];
        float4 w1 = W4[(k4 * 4 + 1) * 32 + jj];
        float4 w2 = W4[(k4 * 4 + 2) * 32 + jj];
        float4 w3 = W4[(k4 * 4 + 3) * 32 + jj];
#pragma unroll
        for (int e = 0; e < 8; ++e) {
            float4 xv = x4[e * 32 + k4];
            fma4(acc[e], w0, xv.x); fma4(acc[e], w1, xv.y);
            fma4(acc[e], w2, xv.z); fma4(acc[e], w3, xv.w);
        }
    }
}
__device__ __forceinline__ float4 comb1_g8(const float4* pb, int jj) {
    float4 s = pb[jj];
#pragma unroll
    for (int gp = 1; gp < 8; ++gp) s = add4(s, pb[gp * 32 + jj]);
    return s;
}
__device__ __forceinline__ float4 comb8_g8(const float4* pb, int it, int jj) {
    float4 s = pb[it * 32 + jj];
#pragma unroll
    for (int gp = 1; gp < 8; ++gp) s = add4(s, pb[(gp * 8 + it) * 32 + jj]);
    return s;
}

// ---------- kernels ----------

// fused: weight transpose (blocks 0..71) + pairflag zero + per-slot edge scan
__global__ __launch_bounds__(256) void k_prep_tr(
    const int* __restrict__ ei, const int* __restrict__ tp,
    const float* __restrict__ inW, const float* __restrict__ ftW,
    const float* __restrict__ teW2, const float* __restrict__ aiW,
    const float* __restrict__ aoW, const float* __restrict__ opW,
    const float* __restrict__ o1W, const float* __restrict__ o2W,
    const float* __restrict__ l1W, const float* __restrict__ l2W,
    float* __restrict__ WT, int* __restrict__ pairflag,
    int* __restrict__ cnt, int2* __restrict__ lst) {
    __shared__ float tile[32][129];
    __shared__ int tps[N_SLOTS];
    __shared__ int lc;
    const int b = blockIdx.x;
    if (threadIdx.x == 0) lc = 0;
    if (b == 0 && threadIdx.x < N_PAIRS) pairflag[threadIdx.x] = 0;
    if (b < 72) {  // block-uniform branch: barriers inside are legal
        int m, r0, rows;
        if (b < 68) { m = b >> 2; r0 = (b & 3) * 32; rows = 128; }
        else { int mm = b - 68; m = 17 + (mm >> 1); r0 = (mm & 1) * 32; rows = 64; }
        const float* src;
        if (m == 0) src = inW;
        else if (m <= 2) src = ftW + (m - 1) * MSTRIDE;
        else if (m <= 4) src = teW2 + (m - 3) * MSTRIDE;
        else if (m <= 10) src = aiW + (m - 5) * MSTRIDE;  // q0,k0,v0,q1,k1,v1
        else if (m <= 12) src = aoW + (m - 11) * MSTRIDE;
        else if (m <= 14) src = opW + (m - 13) * MSTRIDE;
        else if (m == 15) src = o1W;
        else if (m == 16) src = l1W;
        else if (m == 17) src = o2W;
        else src = l2W;
        float* dst = WT + m * MSTRIDE;
        for (int idx = threadIdx.x; idx < 32 * 128; idx += 256) {
            int r = idx >> 7, c = idx & 127;
            tile[r][c] = src[(r0 + r) * 128 + c];
        }
        __syncthreads();
        for (int idx = threadIdx.x; idx < 128 * 32; idx += 256) {
            int k = idx >> 5, jr = idx & 31;
            dst[k * rows + r0 + jr] = tile[jr][k];
        }
    }
    for (int i = threadIdx.x; i < N_SLOTS; i += 256) tps[i] = tp[i];
    __syncthreads();
    // per-slot incident-edge scan
    const int u = tps[b];
    const int4* src4 = (const int4*)ei;
    const int4* dst4 = (const int4*)(ei + N_EDGES);
    for (int e4 = threadIdx.x; e4 < N_EDGES / 4; e4 += 256) {
        int4 s = src4[e4];
        int4 d = dst4[e4];
        int ss[4] = {s.x, s.y, s.z, s.w};
        int dd[4] = {d.x, d.y, d.z, d.w};
#pragma unroll
        for (int t = 0; t < 4; ++t) {
            if (ss[t] == u || dd[t] == u) {
                int nbr = (ss[t] == u) ? dd[t] : ss[t];
                int pos = atomicAdd(&lc, 1);
                if (pos < CAP) lst[b * CAP + pos] = make_int2(e4 * 4 + t, nbr);
            }
        }
    }
    __syncthreads();
    if (threadIdx.x == 0) cnt[b] = lc;
    // flag entries whose neighbor is itself a target (race-avoidance in k_layer)
    int c = min(lc, CAP);
    if (threadIdx.x < c) {
        int2 en = lst[b * CAP + threadIdx.x];
        bool ist = false;
        for (int t = 0; t < N_SLOTS; ++t) ist |= (tps[t] == en.y);
        if (ist) { en.y |= TFLAG; lst[b * CAP + threadIdx.x] = en; }
    }
}

// one block (256 thr) per slot: phase A (x0_u, tf_u, q), phase B edge batches
// (scores/v in LDS), fused reduce: softmax + attn_out + op; layer 0 scatters
// relu(agg) into x; layer 1 runs the emb head, then the last-arriving slot of
// each pair runs the pair head.
__global__ __launch_bounds__(256) void k_layer(
    const float* __restrict__ nf, const float* __restrict__ x,
    const float* __restrict__ ts, const int* __restrict__ tp,
    const int* __restrict__ cnt, const int2* __restrict__ lst,
    const float* __restrict__ WT_in, const float* __restrict__ inb,
    const float* __restrict__ WT_ft, const float* __restrict__ ftb,
    const float* __restrict__ teW1, const float* __restrict__ teb1,
    const float* __restrict__ WT_te2, const float* __restrict__ teb2,
    const float* __restrict__ WT_q, const float* __restrict__ bq,
    const float* __restrict__ WT_k, const float* __restrict__ bk,
    const float* __restrict__ WT_v, const float* __restrict__ bv,
    const float* __restrict__ WT_ao, const float* __restrict__ aob,
    const float* __restrict__ WT_op, const float* __restrict__ opb,
    const float* __restrict__ WT_o1, const float* __restrict__ o1b,
    const float* __restrict__ WT_o2, const float* __restrict__ o2b,
    const float* __restrict__ WT_l1, const float* __restrict__ l1b,
    const float* __restrict__ WT_l2, const float* __restrict__ l2b,
    const float* __restrict__ l3W, const float* __restrict__ l3b,
    float* __restrict__ x_out, float* __restrict__ emb,
    int* __restrict__ pairflag, float* __restrict__ out, int layer) {
    __shared__ __align__(16) float xu[128], x0u[128], tfv[128], qv[128], sv[128];
    __shared__ __align__(16) float xs[8 * 128], t1s[8 * 128], x0s[8 * 128], zs[8 * 128];
    __shared__ __align__(16) float4 pb[8 * 8 * 32];   // 32 KB partials
    __shared__ __align__(16) float vbl[CAP * 128];    // 32 KB values
    __shared__ float scl[CAP * 4];
    __shared__ int nbr_s[8], tf_s[8];
    __shared__ float ts_s[8];
    __shared__ int win_s;
    const int slot = blockIdx.x, tid = threadIdx.x, g = tid >> 5, jj = tid & 31;
    const float scale = 0.17677669529663687f;  // 1/sqrt(32)
    const int u = tp[slot];
    const int c = min(cnt[slot], CAP);

    // ---- phase A ----
    if (tid < 128) xu[tid] = (layer == 0) ? nf[(size_t)u * 128 + tid]
                                          : x[(size_t)u * 128 + tid];
    __syncthreads();
    const float* xeff = xu;
    if (layer == 0) {
        pb[g * 32 + jj] = mv_ks1_g8(WT_in, xu, g, jj);
        __syncthreads();
        if (g == 0)
            *(float4*)(x0u + jj * 4) = add4(comb1_g8(pb, jj), *(const float4*)(inb + jj * 4));
        xeff = x0u;
        __syncthreads();
    }
    pb[g * 32 + jj] = mv_ks1_g8(WT_ft, xeff, g, jj);
    __syncthreads();
    if (g == 0)
        *(float4*)(tfv + jj * 4) = add4(comb1_g8(pb, jj), *(const float4*)(ftb + jj * 4));
    __syncthreads();
    pb[g * 32 + jj] = mv_ks1_g8(WT_q, tfv, g, jj);
    __syncthreads();
    if (g == 0)
        *(float4*)(qv + jj * 4) = add4(comb1_g8(pb, jj), *(const float4*)(bq + jj * 4));
    __syncthreads();

    // ---- phase B: edge batches of 8 (item it == group g) ----
    for (int base = 0; base < c; base += 8) {
        if (tid < 8) {
            int i = base + tid;
            int2 en = (i < c) ? lst[slot * CAP + i] : make_int2(0, 0);
            nbr_s[tid] = en.y & ~TFLAG;
            tf_s[tid] = (en.y & TFLAG) ? 1 : 0;
            ts_s[tid] = (i < c) ? ts[en.x] : 0.f;
        }
        __syncthreads();
        {   // stage neighbor row + time-encoding layer-1 activation
            int e = tid >> 5, c0 = jj * 4;
            const float* srcp = (layer == 0) ? (nf + (size_t)nbr_s[e] * 128 + c0)
                                             : (x + (size_t)nbr_s[e] * 128 + c0);
            float4 v = *(const float4*)srcp;
            float* dstp = (layer == 0) ? xs : x0s;
            *(float4*)(dstp + e * 128 + c0) = v;
            float tse = ts_s[e];
            float4 w = *(const float4*)(teW1 + c0);
            float4 b = *(const float4*)(teb1 + c0);
            *(float4*)(t1s + e * 128 + c0) =
                make_float4(fmaxf(fmaf(tse, w.x, b.x), 0.f),
                            fmaxf(fmaf(tse, w.y, b.y), 0.f),
                            fmaxf(fmaf(tse, w.z, b.z), 0.f),
                            fmaxf(fmaf(tse, w.w, b.w), 0.f));
        }
        __syncthreads();
        if (layer == 0) {  // x0_nbr = inW @ nf[nbr] + inb; persist relu(x0)
            float4 acc[8] = {F4Z, F4Z, F4Z, F4Z, F4Z, F4Z, F4Z, F4Z};
            mv8_g8(WT_in, xs, g, jj, acc);
#pragma unroll
            for (int e = 0; e < 8; ++e) pb[(g * 8 + e) * 32 + jj] = acc[e];
            __syncthreads();
            {
                float4 x0v = add4(comb8_g8(pb, g, jj), *(const float4*)(inb + jj * 4));
                *(float4*)(x0s + g * 128 + jj * 4) = x0v;
                if (base + g < c && !tf_s[g])
                    *(float4*)(x_out + (size_t)nbr_s[g] * 128 + jj * 4) = relu4(x0v);
            }
            __syncthreads();
        }
        {   // z = ftW@x0 + ftb + teW2@t1 + teb2
            float4 acc[8] = {F4Z, F4Z, F4Z, F4Z, F4Z, F4Z, F4Z, F4Z};
            mv8_g8(WT_ft, x0s, g, jj, acc);
#pragma unroll
            for (int e = 0; e < 8; ++e) pb[(g * 8 + e) * 32 + jj] = acc[e];
            __syncthreads();
            float4 za = comb8_g8(pb, g, jj);
            __syncthreads();
            float4 acc2[8] = {F4Z, F4Z, F4Z, F4Z, F4Z, F4Z, F4Z, F4Z};
            mv8_g8(WT_te2, t1s, g, jj, acc2);
#pragma unroll
            for (int e = 0; e < 8; ++e) pb[(g * 8 + e) * 32 + jj] = acc2[e];
            __syncthreads();
            float4 zb = comb8_g8(pb, g, jj);
            float4 z4 = add4(add4(za, zb),
                             add4(*(const float4*)(ftb + jj * 4),
                                  *(const float4*)(teb2 + jj * 4)));
            *(float4*)(zs + g * 128 + jj * 4) = z4;
            __syncthreads();
        }
        {   // k, v, score (v + scores stay in LDS)
            float4 acc[8] = {F4Z, F4Z, F4Z, F4Z, F4Z, F4Z, F4Z, F4Z};
            mv8_g8(WT_k, zs, g, jj, acc);
#pragma unroll
            for (int e = 0; e < 8; ++e) pb[(g * 8 + e) * 32 + jj] = acc[e];
            __syncthreads();
            float4 kk = add4(comb8_g8(pb, g, jj), *(const float4*)(bk + jj * 4));
            __syncthreads();
            float4 acc2[8] = {F4Z, F4Z, F4Z, F4Z, F4Z, F4Z, F4Z, F4Z};
            mv8_g8(WT_v, zs, g, jj, acc2);
#pragma unroll
            for (int e = 0; e < 8; ++e) pb[(g * 8 + e) * 32 + jj] = acc2[e];
            __syncthreads();
            float4 vv = add4(comb8_g8(pb, g, jj), *(const float4*)(bv + jj * 4));
            float4 q4 = *(const float4*)(qv + jj * 4);
            float pr = q4.x * kk.x + q4.y * kk.y + q4.z * kk.z + q4.w * kk.w;
            pr += __shfl_xor(pr, 1);
            pr += __shfl_xor(pr, 2);
            pr += __shfl_xor(pr, 4);  // sum over the 8 lanes of head jj>>3
            if (base + g < c) {
                if ((jj & 7) == 0) scl[(base + g) * 4 + (jj >> 3)] = pr * scale;
                *(float4*)(vbl + (base + g) * 128 + jj * 4) = vv;
            }
            __syncthreads();  // before next batch restages LDS
        }
    }

    // ---- fused reduce: softmax over LDS scores + weighted v-sum ----
    if (tid < 128) {
        int h = tid >> 5;
        if (c > 0) {
            float m = -INFINITY;
            for (int i = 0; i < c; ++i) m = fmaxf(m, scl[i * 4 + h]);
            float l = 0.f, o = 0.f;
            for (int i = 0; i < c; ++i) {
                float p = __expf(scl[i * 4 + h] - m);
                l += p;
                o = fmaf(p, vbl[i * 128 + tid], o);
            }
            sv[tid] = o / l;
        } else {
            sv[tid] = 0.f;
        }
    }
    __syncthreads();
    pb[g * 32 + jj] = mv_ks1_g8(WT_ao, sv, g, jj);
    __syncthreads();
    if (g == 0) {
        float4 z4;
        if (c > 0) z4 = add4(comb1_g8(pb, jj), *(const float4*)(aob + jj * 4));
        else z4 = *(const float4*)(tfv + jj * 4);
        *(float4*)(xu + jj * 4) = z4;  // reuse xu as z
    }
    __syncthreads();
    pb[g * 32 + jj] = mv_ks1_g8(WT_op, xu, g, jj);
    __syncthreads();
    if (layer == 0) {
        if (g == 0) {
            float4 a = relu4(add4(comb1_g8(pb, jj), *(const float4*)(opb + jj * 4)));
            *(float4*)(x_out + (size_t)u * 128 + jj * 4) = a;
        }
        return;
    }
    // ---- layer 1: emb head ----
    if (g == 0)
        *(float4*)(x0u + jj * 4) =
            relu4(add4(comb1_g8(pb, jj), *(const float4*)(opb + jj * 4)));
    __syncthreads();
    pb[g * 32 + jj] = mv_ks1_g8(WT_o1, x0u, g, jj);
    __syncthreads();
    if (g == 0)
        *(float4*)(tfv + jj * 4) =
            relu4(add4(comb1_g8(pb, jj), *(const float4*)(o1b + jj * 4)));
    __syncthreads();
    pb[g * 32 + jj] = mv_ks1_g8_64(WT_o2, tfv, g, jj);
    __syncthreads();
    if (g == 0 && jj < 16) {
        *(float4*)(emb + (size_t)slot * 64 + jj * 4) =
            add4(comb1_g8(pb, jj), *(const float4*)(o2b + jj * 4));
        __threadfence();  // writers flush emb to device scope before the atomic
    }
    __syncthreads();
    // ---- pair handshake: last-arriving slot of pair computes the head ----
    if (tid == 0) win_s = atomicAdd(&pairflag[slot >> 1], 1);
    __syncthreads();
    if (win_s == 0) return;
    __threadfence();  // acquire: partner emb now device-visible
    const int p = slot >> 1;
    if (tid < 128)
        sv[tid] = (tid < 64) ? emb[(size_t)(2 * p) * 64 + tid]
                             : emb[(size_t)(2 * p + 1) * 64 + (tid - 64)];
    __syncthreads();
    pb[g * 32 + jj] = mv_ks1_g8(WT_l1, sv, g, jj);
    __syncthreads();
    if (g == 0)
        *(float4*)(xu + jj * 4) = relu4(add4(comb1_g8(pb, jj), *(const float4*)(l1b + jj * 4)));
    __syncthreads();
    pb[g * 32 + jj] = mv_ks1_g8_64(WT_l2, xu, g, jj);
    __syncthreads();
    if (g == 0 && jj < 16)
        *(float4*)(x0u + jj * 4) = relu4(add4(comb1_g8(pb, jj), *(const float4*)(l2b + jj * 4)));
    __syncthreads();
    if (tid < 64) {
        float v = x0u[tid] * l3W[tid];
        v += __shfl_xor(v, 1);
        v += __shfl_xor(v, 2);
        v += __shfl_xor(v, 4);
        v += __shfl_xor(v, 8);
        v += __shfl_xor(v, 16);
        v += __shfl_xor(v, 32);
        if (tid == 0) out[p] = 1.f / (1.f + __expf(-(v + l3b[0])));
    }
}

// ---------- launch ----------
extern "C" void kernel_launch(void* const* d_in, const int* in_sizes, int n_in,
                              void* d_out, int out_size, void* d_ws, size_t ws_size,
                              hipStream_t stream) {
    const float* nf  = (const float*)d_in[0];
    const int*   ei  = (const int*)d_in[1];
    const float* ts  = (const float*)d_in[2];
    const int*   tp  = (const int*)d_in[3];
    const float* inW = (const float*)d_in[4];
    const float* inb = (const float*)d_in[5];
    const float* teW1 = (const float*)d_in[6];
    const float* teb1 = (const float*)d_in[7];
    const float* teW2 = (const float*)d_in[8];
    const float* teb2 = (const float*)d_in[9];
    const float* aiW = (const float*)d_in[10];
    const float* aib = (const float*)d_in[11];
    const float* aoW = (const float*)d_in[12];
    const float* aob = (const float*)d_in[13];
    const float* ftW = (const float*)d_in[14];
    const float* ftb = (const float*)d_in[15];
    const float* opW = (const float*)d_in[16];
    const float* opb = (const float*)d_in[17];
    const float* o1W = (const float*)d_in[18];
    const float* o1b = (const float*)d_in[19];
    const float* o2W = (const float*)d_in[20];
    const float* o2b = (const float*)d_in[21];
    const float* l1W = (const float*)d_in[22];
    const float* l1b = (const float*)d_in[23];
    const float* l2W = (const float*)d_in[24];
    const float* l2b = (const float*)d_in[25];
    const float* l3W = (const float*)d_in[26];
    const float* l3b = (const float*)d_in[27];
    float* out = (float*)d_out;

    char* ws = (char*)d_ws;
    size_t off = 0;
    float* x    = (float*)(ws + off); off += (size_t)N_NODES * 128 * 4;   // 10.24 MB
    int*   cnt  = (int*)  (ws + off); off += N_SLOTS * 4;
    int2*  lst  = (int2*) (ws + off); off += (size_t)N_SLOTS * CAP * 8;
    float* emb  = (float*)(ws + off); off += N_SLOTS * 64 * 4;
    int*   pfl  = (int*)  (ws + off); off += N_PAIRS * 4;
    float* WT   = (float*)(ws + off); off += (size_t)NMAT * MSTRIDE * 4;  // 1.2 MB

    k_prep_tr<<<N_SLOTS, 256, 0, stream>>>(ei, tp, inW, ftW, teW2, aiW, aoW, opW,
                                           o1W, o2W, l1W, l2W, WT, pfl, cnt, lst);

    for (int l = 0; l < 2; ++l) {
        const float* WT_ft = WT + (1 + l) * MSTRIDE;
        const float* WT_te2 = WT + (3 + l) * MSTRIDE;
        const float* WT_q = WT + (5 + 3 * l) * MSTRIDE;
        const float* WT_k = WT + (6 + 3 * l) * MSTRIDE;
        const float* WT_v = WT + (7 + 3 * l) * MSTRIDE;
        const float* WT_ao = WT + (11 + l) * MSTRIDE;
        const float* WT_op = WT + (13 + l) * MSTRIDE;
        const float* bq = aib + l * 384;
        k_layer<<<N_SLOTS, 256, 0, stream>>>(
            nf, x, ts, tp, cnt, lst,
            WT, inb, WT_ft, ftb + l * 128, teW1 + l * 128, teb1 + l * 128,
            WT_te2, teb2 + l * 128, WT_q, bq, WT_k, bq + 128, WT_v, bq + 256,
            WT_ao, aob + l * 128, WT_op, opb + l * 128,
            WT + 15 * MSTRIDE, o1b, WT + 17 * MSTRIDE, o2b,
            WT + 16 * MSTRIDE, l1b, WT + 18 * MSTRIDE, l2b, l3W, l3b,
            x, emb, pfl, out, l);
    }
}